// Round 1
// baseline (413.737 us; speedup 1.0000x reference)
//
#include <hip/hip_runtime.h>

// B=4, S=2048, D=1024, H=16, Dk=64.  M = B*S = 8192.
// Pipeline: cvt(fp32->bf16) -> proj GEMMs (q/k [bh][s][dk], v [bh][dk][s], q pre-scaled 0.125)
//           -> flash attention (no-max softmax, ones-column row-sum) -> out GEMM (fp32 + bias).
// Workspace requirement: 104 MB.

typedef __bf16 bhalf_t;
typedef __attribute__((ext_vector_type(8))) __bf16 bf16x8;
typedef __attribute__((ext_vector_type(4))) __bf16 bf16x4;
typedef __attribute__((ext_vector_type(4))) float  f32x4;

typedef __attribute__((address_space(1))) void gvoid_t;
typedef __attribute__((address_space(3))) void lvoid_t;
#define GLD16(g, l) __builtin_amdgcn_global_load_lds((const gvoid_t*)(g), (lvoid_t*)(l), 16, 0, 0)

// ---------------------------------------------------------------------------
// fp32 -> bf16 conversion for Q,K,V (8388608 each) and Wq,Wk,Wv,Wo (1048576 each)
// ---------------------------------------------------------------------------
__global__ __launch_bounds__(256) void cvt_all(
    const float* __restrict__ Q, const float* __restrict__ Kin, const float* __restrict__ V,
    const float* __restrict__ Wq, const float* __restrict__ Wk, const float* __restrict__ Wv,
    const float* __restrict__ Wo,
    bhalf_t* __restrict__ Qb, bhalf_t* __restrict__ Kb, bhalf_t* __restrict__ Vb,
    bhalf_t* __restrict__ Wqb, bhalf_t* __restrict__ Wkb, bhalf_t* __restrict__ Wvb,
    bhalf_t* __restrict__ Wob)
{
  size_t t = (size_t)blockIdx.x * 256 + threadIdx.x;   // float4 index
  const float* src; bhalf_t* dst;
  if (t < 2097152)      { src = Q;   dst = Qb; }
  else if (t < 4194304) { src = Kin; dst = Kb; t -= 2097152; }
  else if (t < 6291456) { src = V;   dst = Vb; t -= 4194304; }
  else {
    t -= 6291456;
    int w = (int)(t >> 18); t &= 262143;
    src = (w == 0) ? Wq  : (w == 1) ? Wk  : (w == 2) ? Wv  : Wo;
    dst = (w == 0) ? Wqb : (w == 1) ? Wkb : (w == 2) ? Wvb : Wob;
  }
  float4 f = ((const float4*)src)[t];
  bf16x4 o;
  o.x = (bhalf_t)f.x; o.y = (bhalf_t)f.y; o.z = (bhalf_t)f.z; o.w = (bhalf_t)f.w;
  ((bf16x4*)dst)[t] = o;
}

// ---------------------------------------------------------------------------
// m97-style GEMM core: C[128x128] tile of A[M,1024] @ B[1024,1024(rows=N)]^T
// As/Bs layout: [128 rows][32 k] bf16 (rows 64B). K hardcoded = 1024.
// ---------------------------------------------------------------------------
__device__ __forceinline__ void gemm_core_128(
    const bhalf_t* __restrict__ A, const bhalf_t* __restrict__ B,
    int bm, int bn, bhalf_t* As, bhalf_t* Bs, f32x4 acc[4][4])
{
  const int tid = threadIdx.x, lane = tid & 63, wave = tid >> 6;
  const int wm = wave >> 1, wn = wave & 1;
  const int quad = lane >> 4, tn = lane & 15;
  const int srow = lane >> 2, scol = (lane & 3) * 8;

  const bhalf_t* Ab0 = A + (size_t)(bm * 128 + wave * 16 + srow) * 1024 + scol;
  const bhalf_t* Ab1 = Ab0 + (size_t)64 * 1024;
  const bhalf_t* Bb0 = B + (size_t)(bn * 128 + wave * 16 + srow) * 1024 + scol;
  const bhalf_t* Bb1 = Bb0 + (size_t)64 * 1024;
  bhalf_t* Asw0 = As + wave * 512;  bhalf_t* Asw1 = As + (wave + 4) * 512;
  bhalf_t* Bsw0 = Bs + wave * 512;  bhalf_t* Bsw1 = Bs + (wave + 4) * 512;

  for (int k0 = 0; k0 < 1024; k0 += 32) {
    GLD16(Ab0 + k0, Asw0);
    GLD16(Ab1 + k0, Asw1);
    GLD16(Bb0 + k0, Bsw0);
    GLD16(Bb1 + k0, Bsw1);
    __syncthreads();
    bf16x8 af[4], bfr[4];
#pragma unroll
    for (int i = 0; i < 4; ++i)
      af[i] = *(const bf16x8*)(As + (wm * 64 + i * 16 + tn) * 32 + quad * 8);
#pragma unroll
    for (int j = 0; j < 4; ++j)
      bfr[j] = *(const bf16x8*)(Bs + (wn * 64 + j * 16 + tn) * 32 + quad * 8);
#pragma unroll
    for (int i = 0; i < 4; ++i)
#pragma unroll
      for (int j = 0; j < 4; ++j)
        acc[i][j] = __builtin_amdgcn_mfma_f32_16x16x32_bf16(af[i], bfr[j], acc[i][j], 0, 0, 0);
    __syncthreads();
  }
}

// ---------------------------------------------------------------------------
// Fused q/k/v projection: grid.x = 3*512.  seg 0: q (scale 0.125, [bh][s][dk]),
// seg 1: k ([bh][s][dk]), seg 2: v transposed ([bh][dk][s]).
// ---------------------------------------------------------------------------
__global__ __launch_bounds__(256) void proj_gemm(
    const bhalf_t* __restrict__ Qb, const bhalf_t* __restrict__ Kb, const bhalf_t* __restrict__ Vb,
    const bhalf_t* __restrict__ Wqb, const bhalf_t* __restrict__ Wkb, const bhalf_t* __restrict__ Wvb,
    const float* __restrict__ bq, const float* __restrict__ bk, const float* __restrict__ bv,
    bhalf_t* __restrict__ qo, bhalf_t* __restrict__ ko, bhalf_t* __restrict__ vto)
{
  __shared__ bhalf_t As[4096];
  __shared__ bhalf_t Bs[4096];
  const int seg = blockIdx.x >> 9;
  const int idx = blockIdx.x & 511;
  const int bm = idx >> 3, bn = idx & 7;

  const bhalf_t *A, *Bw; const float* bias; bhalf_t* out; float scale; int mode;
  if (seg == 0)      { A = Qb; Bw = Wqb; bias = bq; out = qo;  scale = 0.125f; mode = 0; }
  else if (seg == 1) { A = Kb; Bw = Wkb; bias = bk; out = ko;  scale = 1.0f;   mode = 0; }
  else               { A = Vb; Bw = Wvb; bias = bv; out = vto; scale = 1.0f;   mode = 1; }

  f32x4 acc[4][4];
#pragma unroll
  for (int i = 0; i < 4; ++i)
#pragma unroll
    for (int j = 0; j < 4; ++j)
      acc[i][j] = (f32x4){0.f, 0.f, 0.f, 0.f};

  gemm_core_128(A, Bw, bm, bn, As, Bs, acc);

  const int lane = threadIdx.x & 63, wave = threadIdx.x >> 6;
  const int wm = wave >> 1, wn = wave & 1, quad = lane >> 4, tn = lane & 15;
#pragma unroll
  for (int i = 0; i < 4; ++i)
#pragma unroll
    for (int j = 0; j < 4; ++j) {
      const int n = bn * 128 + wn * 64 + j * 16 + tn;
      const float bsv = bias[n];
      const int h = n >> 6, dk = n & 63;
#pragma unroll
      for (int r = 0; r < 4; ++r) {
        const int m = bm * 128 + wm * 64 + i * 16 + quad * 4 + r;
        const int b = m >> 11, s = m & 2047;
        const float v = (acc[i][j][r] + bsv) * scale;
        size_t addr;
        if (mode == 0) addr = (((size_t)(b * 16 + h)) * 2048 + s) * 64 + dk;
        else           addr = (((size_t)(b * 16 + h)) * 64 + dk) * 2048 + s;
        out[addr] = (bhalf_t)v;
      }
    }
}

// ---------------------------------------------------------------------------
// Output projection: attn_out[8192,1024] bf16 @ Wo[1024,1024]^T + bo -> fp32 d_out
// ---------------------------------------------------------------------------
__global__ __launch_bounds__(256) void out_gemm(
    const bhalf_t* __restrict__ A, const bhalf_t* __restrict__ Bw,
    const float* __restrict__ bias, float* __restrict__ Cout)
{
  __shared__ bhalf_t As[4096];
  __shared__ bhalf_t Bs[4096];
  const int bm = blockIdx.x >> 3, bn = blockIdx.x & 7;

  f32x4 acc[4][4];
#pragma unroll
  for (int i = 0; i < 4; ++i)
#pragma unroll
    for (int j = 0; j < 4; ++j)
      acc[i][j] = (f32x4){0.f, 0.f, 0.f, 0.f};

  gemm_core_128(A, Bw, bm, bn, As, Bs, acc);

  const int lane = threadIdx.x & 63, wave = threadIdx.x >> 6;
  const int wm = wave >> 1, wn = wave & 1, quad = lane >> 4, tn = lane & 15;
#pragma unroll
  for (int i = 0; i < 4; ++i)
#pragma unroll
    for (int j = 0; j < 4; ++j) {
      const int n = bn * 128 + wn * 64 + j * 16 + tn;
      const float bsv = bias[n];
#pragma unroll
      for (int r = 0; r < 4; ++r) {
        const int m = bm * 128 + wm * 64 + i * 16 + quad * 4 + r;
        Cout[(size_t)m * 1024 + n] = acc[i][j][r] + bsv;
      }
    }
}

// ---------------------------------------------------------------------------
// Flash attention (non-causal, no-max-subtraction softmax; scores pre-scaled via q).
// Block: 256 thr = 4 waves; 64 q-rows/block (16/wave); KV tiles of 64.
// Klds:  [dk-half][64 kv][32 dk]   (8 KB)    Vtlds: [kv-half][64 dk][32 kv] (8 KB)
// Plds:  per-wave [16 q][72 kv-padded] bf16  (9 KB)
// Row-sum l accumulated by MFMA against a ones-column B fragment.
// ---------------------------------------------------------------------------
__global__ __launch_bounds__(256) void attn_kernel(
    const bhalf_t* __restrict__ qp, const bhalf_t* __restrict__ kp,
    const bhalf_t* __restrict__ vtp, bhalf_t* __restrict__ outp)
{
  __shared__ bhalf_t Klds[4096];
  __shared__ bhalf_t Vtlds[4096];
  __shared__ bhalf_t Plds[4][16 * 72];

  const int tid = threadIdx.x, lane = tid & 63, wave = tid >> 6;
  const int quad = lane >> 4, tn = lane & 15;
  const int bh = blockIdx.y, qt = blockIdx.x;

  // Q fragments for this wave's 16 rows (held in regs all kernel).
  const bhalf_t* qbase = qp + (((size_t)bh * 2048) + qt * 64 + wave * 16) * 64;
  const bf16x8 qa0 = *(const bf16x8*)(qbase + tn * 64 + quad * 8);
  const bf16x8 qa1 = *(const bf16x8*)(qbase + tn * 64 + 32 + quad * 8);

  // ones-column B fragment: B[k][n] = (n==0)
  bf16x8 onesf;
#pragma unroll
  for (int j = 0; j < 8; ++j) onesf[j] = (tn == 0) ? (bhalf_t)1.0f : (bhalf_t)0.0f;

  f32x4 Oacc[4];
#pragma unroll
  for (int t2 = 0; t2 < 4; ++t2) Oacc[t2] = (f32x4){0.f, 0.f, 0.f, 0.f};
  f32x4 Lacc = (f32x4){0.f, 0.f, 0.f, 0.f};

  const bhalf_t* kbase  = kp  + (size_t)bh * 2048 * 64;
  const bhalf_t* vtbase = vtp + (size_t)bh * 64 * 2048;
  const int srow = lane >> 2, scol8 = (lane & 3) * 8;

  for (int kv0 = 0; kv0 < 2048; kv0 += 64) {
    // stage K tile and Vt tile (8 KB each, 2 chunks of 1 KB per wave per array)
#pragma unroll
    for (int ci = 0; ci < 2; ++ci) {
      const int c = wave + ci * 4;
      const int half = c >> 2;                  // dk-half for K, kv-half for Vt
      const int rr = (c & 3) * 16 + srow;       // kv row for K, dk row for Vt
      GLD16(kbase + (size_t)(kv0 + rr) * 64 + half * 32 + scol8, Klds + c * 512);
      GLD16(vtbase + (size_t)rr * 2048 + kv0 + half * 32 + scol8, Vtlds + c * 512);
    }
    __syncthreads();

    // S = q @ k^T  (already scaled by 1/8 via q)
    f32x4 Sv[4];
#pragma unroll
    for (int t2 = 0; t2 < 4; ++t2) {
      f32x4 z = (f32x4){0.f, 0.f, 0.f, 0.f};
      bf16x8 kb0 = *(const bf16x8*)(Klds + (t2 * 16 + tn) * 32 + quad * 8);
      bf16x8 kb1 = *(const bf16x8*)(Klds + 2048 + (t2 * 16 + tn) * 32 + quad * 8);
      z = __builtin_amdgcn_mfma_f32_16x16x32_bf16(qa0, kb0, z, 0, 0, 0);
      z = __builtin_amdgcn_mfma_f32_16x16x32_bf16(qa1, kb1, z, 0, 0, 0);
      Sv[t2] = z;
    }

    // P = exp(S) -> bf16 -> LDS (C-layout to A-layout transform)
    bhalf_t* P = &Plds[wave][0];
#pragma unroll
    for (int t2 = 0; t2 < 4; ++t2)
#pragma unroll
      for (int r = 0; r < 4; ++r)
        P[(quad * 4 + r) * 72 + t2 * 16 + tn] = (bhalf_t)__expf(Sv[t2][r]);

    const bf16x8 pa0 = *(const bf16x8*)(P + tn * 72 + quad * 8);
    const bf16x8 pa1 = *(const bf16x8*)(P + tn * 72 + 32 + quad * 8);

    // O += P @ V ; L += P @ ones
#pragma unroll
    for (int t2 = 0; t2 < 4; ++t2) {
      bf16x8 vb0 = *(const bf16x8*)(Vtlds + (t2 * 16 + tn) * 32 + quad * 8);
      bf16x8 vb1 = *(const bf16x8*)(Vtlds + 2048 + (t2 * 16 + tn) * 32 + quad * 8);
      Oacc[t2] = __builtin_amdgcn_mfma_f32_16x16x32_bf16(pa0, vb0, Oacc[t2], 0, 0, 0);
      Oacc[t2] = __builtin_amdgcn_mfma_f32_16x16x32_bf16(pa1, vb1, Oacc[t2], 0, 0, 0);
    }
    Lacc = __builtin_amdgcn_mfma_f32_16x16x32_bf16(pa0, onesf, Lacc, 0, 0, 0);
    Lacc = __builtin_amdgcn_mfma_f32_16x16x32_bf16(pa1, onesf, Lacc, 0, 0, 0);
    __syncthreads();
  }

  // normalize and store: out[b][s][h*64+dk] bf16 (row-major [8192,1024])
  float linv[4];
#pragma unroll
  for (int r = 0; r < 4; ++r) {
    float l = __shfl(Lacc[r], lane & 48);   // col-0 lane of this quad holds the row sum
    linv[r] = 1.0f / l;
  }
  const int b = bh >> 4, h = bh & 15;
  const int srow0 = qt * 64 + wave * 16 + quad * 4;
#pragma unroll
  for (int t2 = 0; t2 < 4; ++t2)
#pragma unroll
    for (int r = 0; r < 4; ++r) {
      const int s = srow0 + r;
      const int dk = t2 * 16 + tn;
      outp[((size_t)(b * 2048 + s)) * 1024 + h * 64 + dk] = (bhalf_t)(Oacc[t2][r] * linv[r]);
    }
}

// ---------------------------------------------------------------------------
extern "C" void kernel_launch(void* const* d_in, const int* in_sizes, int n_in,
                              void* d_out, int out_size, void* d_ws, size_t ws_size,
                              hipStream_t stream)
{
  const float* Q  = (const float*)d_in[0];
  const float* K  = (const float*)d_in[1];
  const float* V  = (const float*)d_in[2];
  const float* Wq = (const float*)d_in[3];
  const float* bq = (const float*)d_in[4];
  const float* Wk = (const float*)d_in[5];
  const float* bk = (const float*)d_in[6];
  const float* Wv = (const float*)d_in[7];
  const float* bv = (const float*)d_in[8];
  const float* Wo = (const float*)d_in[9];
  const float* bo = (const float*)d_in[10];

  char* ws = (char*)d_ws;
  const size_t SZ = 8192ull * 1024 * 2;   // 16 MB  [8192,1024] bf16
  const size_t WZ = 1024ull * 1024 * 2;   //  2 MB  [1024,1024] bf16
  bhalf_t* Qb   = (bhalf_t*)(ws);
  bhalf_t* Kb   = (bhalf_t*)(ws + SZ);
  bhalf_t* Vb   = (bhalf_t*)(ws + 2 * SZ);
  bhalf_t* Wqb  = (bhalf_t*)(ws + 3 * SZ);
  bhalf_t* Wkb  = (bhalf_t*)(ws + 3 * SZ + WZ);
  bhalf_t* Wvb  = (bhalf_t*)(ws + 3 * SZ + 2 * WZ);
  bhalf_t* Wob  = (bhalf_t*)(ws + 3 * SZ + 3 * WZ);
  bhalf_t* q_p  = (bhalf_t*)(ws + 3 * SZ + 4 * WZ);
  bhalf_t* k_p  = (bhalf_t*)(ws + 4 * SZ + 4 * WZ);
  bhalf_t* vt_p = (bhalf_t*)(ws + 5 * SZ + 4 * WZ);
  bhalf_t* attn_o = Qb;   // alias: Qb is dead after proj_gemm

  cvt_all<<<28672, 256, 0, stream>>>(Q, K, V, Wq, Wk, Wv, Wo,
                                     Qb, Kb, Vb, Wqb, Wkb, Wvb, Wob);
  proj_gemm<<<1536, 256, 0, stream>>>(Qb, Kb, Vb, Wqb, Wkb, Wvb,
                                      bq, bk, bv, q_p, k_p, vt_p);
  attn_kernel<<<dim3(32, 64), 256, 0, stream>>>(q_p, k_p, vt_p, attn_o);
  out_gemm<<<512, 256, 0, stream>>>(attn_o, Wob, bo, (float*)d_out);
}

// Round 2
// 373.059 us; speedup vs baseline: 1.1090x; 1.1090x over previous
//
#include <hip/hip_runtime.h>

// B=4, S=2048, D=1024, H=16, Dk=64.  M = B*S = 8192.
// Pipeline: cvt(fp32->bf16) -> proj GEMMs (q/k [bh][s][dk], v [bh][dk][s], q pre-scaled 0.125)
//           -> flash attention v2 (S^T via 32x32x16, per-lane-q softmax) -> out GEMM.
// Workspace requirement: 104 MB.

typedef __bf16 bhalf_t;
typedef __attribute__((ext_vector_type(8)))  __bf16 bf16x8;
typedef __attribute__((ext_vector_type(4)))  __bf16 bf16x4;
typedef __attribute__((ext_vector_type(4)))  float  f32x4;
typedef __attribute__((ext_vector_type(16))) float  f32x16;

typedef __attribute__((address_space(1))) void gvoid_t;
typedef __attribute__((address_space(3))) void lvoid_t;
#define GLD16(g, l) __builtin_amdgcn_global_load_lds((const gvoid_t*)(g), (lvoid_t*)(l), 16, 0, 0)

// ---------------------------------------------------------------------------
// fp32 -> bf16 conversion for Q,K,V and Wq,Wk,Wv,Wo
// ---------------------------------------------------------------------------
__global__ __launch_bounds__(256) void cvt_all(
    const float* __restrict__ Q, const float* __restrict__ Kin, const float* __restrict__ V,
    const float* __restrict__ Wq, const float* __restrict__ Wk, const float* __restrict__ Wv,
    const float* __restrict__ Wo,
    bhalf_t* __restrict__ Qb, bhalf_t* __restrict__ Kb, bhalf_t* __restrict__ Vb,
    bhalf_t* __restrict__ Wqb, bhalf_t* __restrict__ Wkb, bhalf_t* __restrict__ Wvb,
    bhalf_t* __restrict__ Wob)
{
  size_t t = (size_t)blockIdx.x * 256 + threadIdx.x;   // float4 index
  const float* src; bhalf_t* dst;
  if (t < 2097152)      { src = Q;   dst = Qb; }
  else if (t < 4194304) { src = Kin; dst = Kb; t -= 2097152; }
  else if (t < 6291456) { src = V;   dst = Vb; t -= 4194304; }
  else {
    t -= 6291456;
    int w = (int)(t >> 18); t &= 262143;
    src = (w == 0) ? Wq  : (w == 1) ? Wk  : (w == 2) ? Wv  : Wo;
    dst = (w == 0) ? Wqb : (w == 1) ? Wkb : (w == 2) ? Wvb : Wob;
  }
  float4 f = ((const float4*)src)[t];
  bf16x4 o;
  o.x = (bhalf_t)f.x; o.y = (bhalf_t)f.y; o.z = (bhalf_t)f.z; o.w = (bhalf_t)f.w;
  ((bf16x4*)dst)[t] = o;
}

// ---------------------------------------------------------------------------
// m97-style GEMM core: C[128x128] tile of A[M,1024] @ B[1024,1024(rows=N)]^T
// ---------------------------------------------------------------------------
__device__ __forceinline__ void gemm_core_128(
    const bhalf_t* __restrict__ A, const bhalf_t* __restrict__ B,
    int bm, int bn, bhalf_t* As, bhalf_t* Bs, f32x4 acc[4][4])
{
  const int tid = threadIdx.x, lane = tid & 63, wave = tid >> 6;
  const int wm = wave >> 1, wn = wave & 1;
  const int quad = lane >> 4, tn = lane & 15;
  const int srow = lane >> 2, scol = (lane & 3) * 8;

  const bhalf_t* Ab0 = A + (size_t)(bm * 128 + wave * 16 + srow) * 1024 + scol;
  const bhalf_t* Ab1 = Ab0 + (size_t)64 * 1024;
  const bhalf_t* Bb0 = B + (size_t)(bn * 128 + wave * 16 + srow) * 1024 + scol;
  const bhalf_t* Bb1 = Bb0 + (size_t)64 * 1024;
  bhalf_t* Asw0 = As + wave * 512;  bhalf_t* Asw1 = As + (wave + 4) * 512;
  bhalf_t* Bsw0 = Bs + wave * 512;  bhalf_t* Bsw1 = Bs + (wave + 4) * 512;

  for (int k0 = 0; k0 < 1024; k0 += 32) {
    GLD16(Ab0 + k0, Asw0);
    GLD16(Ab1 + k0, Asw1);
    GLD16(Bb0 + k0, Bsw0);
    GLD16(Bb1 + k0, Bsw1);
    __syncthreads();
    bf16x8 af[4], bfr[4];
#pragma unroll
    for (int i = 0; i < 4; ++i)
      af[i] = *(const bf16x8*)(As + (wm * 64 + i * 16 + tn) * 32 + quad * 8);
#pragma unroll
    for (int j = 0; j < 4; ++j)
      bfr[j] = *(const bf16x8*)(Bs + (wn * 64 + j * 16 + tn) * 32 + quad * 8);
#pragma unroll
    for (int i = 0; i < 4; ++i)
#pragma unroll
      for (int j = 0; j < 4; ++j)
        acc[i][j] = __builtin_amdgcn_mfma_f32_16x16x32_bf16(af[i], bfr[j], acc[i][j], 0, 0, 0);
    __syncthreads();
  }
}

// ---------------------------------------------------------------------------
// Fused q/k/v projection
// ---------------------------------------------------------------------------
__global__ __launch_bounds__(256) void proj_gemm(
    const bhalf_t* __restrict__ Qb, const bhalf_t* __restrict__ Kb, const bhalf_t* __restrict__ Vb,
    const bhalf_t* __restrict__ Wqb, const bhalf_t* __restrict__ Wkb, const bhalf_t* __restrict__ Wvb,
    const float* __restrict__ bq, const float* __restrict__ bk, const float* __restrict__ bv,
    bhalf_t* __restrict__ qo, bhalf_t* __restrict__ ko, bhalf_t* __restrict__ vto)
{
  __shared__ bhalf_t As[4096];
  __shared__ bhalf_t Bs[4096];
  const int seg = blockIdx.x >> 9;
  const int idx = blockIdx.x & 511;
  const int bm = idx >> 3, bn = idx & 7;

  const bhalf_t *A, *Bw; const float* bias; bhalf_t* out; float scale; int mode;
  if (seg == 0)      { A = Qb; Bw = Wqb; bias = bq; out = qo;  scale = 0.125f; mode = 0; }
  else if (seg == 1) { A = Kb; Bw = Wkb; bias = bk; out = ko;  scale = 1.0f;   mode = 0; }
  else               { A = Vb; Bw = Wvb; bias = bv; out = vto; scale = 1.0f;   mode = 1; }

  f32x4 acc[4][4];
#pragma unroll
  for (int i = 0; i < 4; ++i)
#pragma unroll
    for (int j = 0; j < 4; ++j)
      acc[i][j] = (f32x4){0.f, 0.f, 0.f, 0.f};

  gemm_core_128(A, Bw, bm, bn, As, Bs, acc);

  const int lane = threadIdx.x & 63, wave = threadIdx.x >> 6;
  const int wm = wave >> 1, wn = wave & 1, quad = lane >> 4, tn = lane & 15;
#pragma unroll
  for (int i = 0; i < 4; ++i)
#pragma unroll
    for (int j = 0; j < 4; ++j) {
      const int n = bn * 128 + wn * 64 + j * 16 + tn;
      const float bsv = bias[n];
      const int h = n >> 6, dk = n & 63;
#pragma unroll
      for (int r = 0; r < 4; ++r) {
        const int m = bm * 128 + wm * 64 + i * 16 + quad * 4 + r;
        const int b = m >> 11, s = m & 2047;
        const float v = (acc[i][j][r] + bsv) * scale;
        size_t addr;
        if (mode == 0) addr = (((size_t)(b * 16 + h)) * 2048 + s) * 64 + dk;
        else           addr = (((size_t)(b * 16 + h)) * 64 + dk) * 2048 + s;
        out[addr] = (bhalf_t)v;
      }
    }
}

// ---------------------------------------------------------------------------
// Output projection
// ---------------------------------------------------------------------------
__global__ __launch_bounds__(256) void out_gemm(
    const bhalf_t* __restrict__ A, const bhalf_t* __restrict__ Bw,
    const float* __restrict__ bias, float* __restrict__ Cout)
{
  __shared__ bhalf_t As[4096];
  __shared__ bhalf_t Bs[4096];
  const int bm = blockIdx.x >> 3, bn = blockIdx.x & 7;

  f32x4 acc[4][4];
#pragma unroll
  for (int i = 0; i < 4; ++i)
#pragma unroll
    for (int j = 0; j < 4; ++j)
      acc[i][j] = (f32x4){0.f, 0.f, 0.f, 0.f};

  gemm_core_128(A, Bw, bm, bn, As, Bs, acc);

  const int lane = threadIdx.x & 63, wave = threadIdx.x >> 6;
  const int wm = wave >> 1, wn = wave & 1, quad = lane >> 4, tn = lane & 15;
#pragma unroll
  for (int i = 0; i < 4; ++i)
#pragma unroll
    for (int j = 0; j < 4; ++j) {
      const int n = bn * 128 + wn * 64 + j * 16 + tn;
      const float bsv = bias[n];
#pragma unroll
      for (int r = 0; r < 4; ++r) {
        const int m = bm * 128 + wm * 64 + i * 16 + quad * 4 + r;
        Cout[(size_t)m * 1024 + n] = acc[i][j][r] + bsv;
      }
    }
}

// ---------------------------------------------------------------------------
// Flash attention v2.  Block = 4 waves, 128 q rows (32/wave), kv tiles of 64.
// S^T = K @ Q^T via mfma_32x32x16 (A=K from LDS, B=Q in regs): each lane owns
// one q column -> L row-sum is pure VALU + one shfl_xor(32).
// P stored [q][kv] stride 72 (packed b64 writes), read back as PV B-operand.
// PV: O^T = V^T @ P  (A=V^T from LDS).  K/Vt staged with XOR-swizzled GLD16.
// ---------------------------------------------------------------------------
__global__ __launch_bounds__(256, 4) void attn_kernel(
    const bhalf_t* __restrict__ qp, const bhalf_t* __restrict__ kp,
    const bhalf_t* __restrict__ vtp, bhalf_t* __restrict__ outp)
{
  __shared__ bhalf_t Klds[4096];    // [64 kv][64 dk], 16B chunks XOR-swizzled
  __shared__ bhalf_t Vtlds[4096];   // [64 dk][64 kv], 16B chunks XOR-swizzled
  __shared__ bhalf_t Plds[4 * 32 * 72];  // per-wave [32 q][72 kv-padded]

  const int tid = threadIdx.x, lane = tid & 63, wave = tid >> 6;
  const int q31 = lane & 31, h = lane >> 5;
  const int bh = blockIdx.y, qt = blockIdx.x;

  // Q B-fragments: lane holds B[k=dk][n=q31]: q row fixed, dk = ks*16 + h*8 + j
  const bhalf_t* qbase = qp + (((size_t)bh * 2048) + qt * 128 + wave * 32 + q31) * 64;
  bf16x8 qf[4];
#pragma unroll
  for (int ks = 0; ks < 4; ++ks)
    qf[ks] = *(const bf16x8*)(qbase + ks * 16 + h * 8);

  f32x16 Ot[2];
#pragma unroll
  for (int mb = 0; mb < 2; ++mb)
#pragma unroll
    for (int i = 0; i < 16; ++i) Ot[mb][i] = 0.f;
  float Lp = 0.f;

  const bhalf_t* kbase  = kp  + (size_t)bh * 2048 * 64;
  const bhalf_t* vtbase = vtp + (size_t)bh * 64 * 2048;
  bhalf_t* Pw = Plds + wave * 2304;

  const int rloc = lane >> 3;                 // staging: row within 8-row chunk
  const int cg8  = ((lane & 7) ^ rloc) * 8;   // swizzled source chunk (elems)
  const int asw0 = ((0 + h) ^ (q31 & 7)) * 8; // A-frag swizzle per ks (c = 2ks+h)
  const int asw1 = ((2 + h) ^ (q31 & 7)) * 8;
  const int asw2 = ((4 + h) ^ (q31 & 7)) * 8;
  const int asw3 = ((6 + h) ^ (q31 & 7)) * 8;
  const int aswz[4] = {asw0, asw1, asw2, asw3};

  for (int kv0 = 0; kv0 < 2048; kv0 += 64) {
    // stage K [64][64] and Vt [64][64]: 8 GLD16 of 1KB each per block
#pragma unroll
    for (int i = 0; i < 2; ++i) {
      const int r0 = (wave * 2 + i) * 8;
      GLD16(kbase + (size_t)(kv0 + r0 + rloc) * 64 + cg8, Klds + r0 * 64);
      GLD16(vtbase + (size_t)(r0 + rloc) * 2048 + kv0 + cg8, Vtlds + r0 * 64);
    }
    __syncthreads();

    // S^T (64 kv x 32 q) + exp + packed P write
#pragma unroll
    for (int mb = 0; mb < 2; ++mb) {
      f32x16 S;
#pragma unroll
      for (int i = 0; i < 16; ++i) S[i] = 0.f;
      const int rbase = mb * 32 + q31;
#pragma unroll
      for (int ks = 0; ks < 4; ++ks) {
        const bf16x8 ka = *(const bf16x8*)(Klds + rbase * 64 + ks * 16 + (aswz[ks] - ks * 16));
        S = __builtin_amdgcn_mfma_f32_32x32x16_bf16(ka, qf[ks], S, 0, 0, 0);
      }
#pragma unroll
      for (int g = 0; g < 4; ++g) {
        const float e0 = __expf(S[4 * g + 0]);
        const float e1 = __expf(S[4 * g + 1]);
        const float e2 = __expf(S[4 * g + 2]);
        const float e3 = __expf(S[4 * g + 3]);
        Lp += (e0 + e1) + (e2 + e3);
        bf16x4 pk;
        pk.x = (bhalf_t)e0; pk.y = (bhalf_t)e1; pk.z = (bhalf_t)e2; pk.w = (bhalf_t)e3;
        *(bf16x4*)(Pw + q31 * 72 + mb * 32 + g * 8 + h * 4) = pk;
      }
    }

    // O^T += V^T @ P  (wave-local P, no barrier needed between write & read)
#pragma unroll
    for (int ks = 0; ks < 4; ++ks) {
      const bf16x8 pb = *(const bf16x8*)(Pw + q31 * 72 + ks * 16 + h * 8);
#pragma unroll
      for (int mb = 0; mb < 2; ++mb) {
        const bf16x8 va = *(const bf16x8*)(Vtlds + (mb * 32 + q31) * 64 + aswz[ks]);
        Ot[mb] = __builtin_amdgcn_mfma_f32_32x32x16_bf16(va, pb, Ot[mb], 0, 0, 0);
      }
    }
    __syncthreads();
  }

  // normalize (per-lane q) and store packed bf16x4
  const float Lt = Lp + __shfl_xor(Lp, 32, 64);
  const float linv = 1.0f / Lt;
  const int b = bh >> 4, hh = bh & 15;
  const int s = qt * 128 + wave * 32 + q31;
  bhalf_t* ob = outp + ((size_t)(b * 2048 + s)) * 1024 + hh * 64;
#pragma unroll
  for (int mb = 0; mb < 2; ++mb)
#pragma unroll
    for (int g = 0; g < 4; ++g) {
      bf16x4 o;
      o.x = (bhalf_t)(Ot[mb][4 * g + 0] * linv);
      o.y = (bhalf_t)(Ot[mb][4 * g + 1] * linv);
      o.z = (bhalf_t)(Ot[mb][4 * g + 2] * linv);
      o.w = (bhalf_t)(Ot[mb][4 * g + 3] * linv);
      *(bf16x4*)(ob + mb * 32 + g * 8 + h * 4) = o;
    }
}

// ---------------------------------------------------------------------------
extern "C" void kernel_launch(void* const* d_in, const int* in_sizes, int n_in,
                              void* d_out, int out_size, void* d_ws, size_t ws_size,
                              hipStream_t stream)
{
  const float* Q  = (const float*)d_in[0];
  const float* K  = (const float*)d_in[1];
  const float* V  = (const float*)d_in[2];
  const float* Wq = (const float*)d_in[3];
  const float* bq = (const float*)d_in[4];
  const float* Wk = (const float*)d_in[5];
  const float* bk = (const float*)d_in[6];
  const float* Wv = (const float*)d_in[7];
  const float* bv = (const float*)d_in[8];
  const float* Wo = (const float*)d_in[9];
  const float* bo = (const float*)d_in[10];

  char* ws = (char*)d_ws;
  const size_t SZ = 8192ull * 1024 * 2;   // 16 MB  [8192,1024] bf16
  const size_t WZ = 1024ull * 1024 * 2;   //  2 MB  [1024,1024] bf16
  bhalf_t* Qb   = (bhalf_t*)(ws);
  bhalf_t* Kb   = (bhalf_t*)(ws + SZ);
  bhalf_t* Vb   = (bhalf_t*)(ws + 2 * SZ);
  bhalf_t* Wqb  = (bhalf_t*)(ws + 3 * SZ);
  bhalf_t* Wkb  = (bhalf_t*)(ws + 3 * SZ + WZ);
  bhalf_t* Wvb  = (bhalf_t*)(ws + 3 * SZ + 2 * WZ);
  bhalf_t* Wob  = (bhalf_t*)(ws + 3 * SZ + 3 * WZ);
  bhalf_t* q_p  = (bhalf_t*)(ws + 3 * SZ + 4 * WZ);
  bhalf_t* k_p  = (bhalf_t*)(ws + 4 * SZ + 4 * WZ);
  bhalf_t* vt_p = (bhalf_t*)(ws + 5 * SZ + 4 * WZ);
  bhalf_t* attn_o = Qb;   // alias: Qb is dead after proj_gemm

  cvt_all<<<28672, 256, 0, stream>>>(Q, K, V, Wq, Wk, Wv, Wo,
                                     Qb, Kb, Vb, Wqb, Wkb, Wvb, Wob);
  proj_gemm<<<1536, 256, 0, stream>>>(Qb, Kb, Vb, Wqb, Wkb, Wvb,
                                      bq, bk, bv, q_p, k_p, vt_p);
  attn_kernel<<<dim3(16, 64), 256, 0, stream>>>(q_p, k_p, vt_p, attn_o);
  out_gemm<<<512, 256, 0, stream>>>(attn_o, Wob, bo, (float*)d_out);
}

// Round 3
// 348.841 us; speedup vs baseline: 1.1860x; 1.0694x over previous
//
#include <hip/hip_runtime.h>

// B=4, S=2048, D=1024, H=16, Dk=64.  M = B*S = 8192.
// cvt(fp32->bf16) -> proj GEMMs (q/k [bh][s][dk], v^T sigma-permuted [bh][dk][s],
// q pre-scaled 0.125*log2e) -> flash attn v3 (S^T 32x32x16, P-in-regs via sigma
// trick, 64 q/wave) -> out GEMM.  Workspace: 104 MB.

typedef __bf16 bhalf_t;
typedef __attribute__((ext_vector_type(8)))  __bf16 bf16x8;
typedef __attribute__((ext_vector_type(4)))  __bf16 bf16x4;
typedef __attribute__((ext_vector_type(4)))  float  f32x4;
typedef __attribute__((ext_vector_type(16))) float  f32x16;

typedef __attribute__((address_space(1))) void gvoid_t;
typedef __attribute__((address_space(3))) void lvoid_t;
#define GLD16(g, l) __builtin_amdgcn_global_load_lds((const gvoid_t*)(g), (lvoid_t*)(l), 16, 0, 0)

// ---------------------------------------------------------------------------
__global__ __launch_bounds__(256) void cvt_all(
    const float* __restrict__ Q, const float* __restrict__ Kin, const float* __restrict__ V,
    const float* __restrict__ Wq, const float* __restrict__ Wk, const float* __restrict__ Wv,
    const float* __restrict__ Wo,
    bhalf_t* __restrict__ Qb, bhalf_t* __restrict__ Kb, bhalf_t* __restrict__ Vb,
    bhalf_t* __restrict__ Wqb, bhalf_t* __restrict__ Wkb, bhalf_t* __restrict__ Wvb,
    bhalf_t* __restrict__ Wob)
{
  size_t t = (size_t)blockIdx.x * 256 + threadIdx.x;   // float4 index
  const float* src; bhalf_t* dst;
  if (t < 2097152)      { src = Q;   dst = Qb; }
  else if (t < 4194304) { src = Kin; dst = Kb; t -= 2097152; }
  else if (t < 6291456) { src = V;   dst = Vb; t -= 4194304; }
  else {
    t -= 6291456;
    int w = (int)(t >> 18); t &= 262143;
    src = (w == 0) ? Wq  : (w == 1) ? Wk  : (w == 2) ? Wv  : Wo;
    dst = (w == 0) ? Wqb : (w == 1) ? Wkb : (w == 2) ? Wvb : Wob;
  }
  float4 f = ((const float4*)src)[t];
  bf16x4 o;
  o.x = (bhalf_t)f.x; o.y = (bhalf_t)f.y; o.z = (bhalf_t)f.z; o.w = (bhalf_t)f.w;
  ((bf16x4*)dst)[t] = o;
}

// ---------------------------------------------------------------------------
// m97-style GEMM core: C[128x128] tile of A[M,1024] @ B[1024,1024(rows=N)]^T
// ---------------------------------------------------------------------------
__device__ __forceinline__ void gemm_core_128(
    const bhalf_t* __restrict__ A, const bhalf_t* __restrict__ B,
    int bm, int bn, bhalf_t* As, bhalf_t* Bs, f32x4 acc[4][4])
{
  const int tid = threadIdx.x, lane = tid & 63, wave = tid >> 6;
  const int wm = wave >> 1, wn = wave & 1;
  const int quad = lane >> 4, tn = lane & 15;
  const int srow = lane >> 2, scol = (lane & 3) * 8;

  const bhalf_t* Ab0 = A + (size_t)(bm * 128 + wave * 16 + srow) * 1024 + scol;
  const bhalf_t* Ab1 = Ab0 + (size_t)64 * 1024;
  const bhalf_t* Bb0 = B + (size_t)(bn * 128 + wave * 16 + srow) * 1024 + scol;
  const bhalf_t* Bb1 = Bb0 + (size_t)64 * 1024;
  bhalf_t* Asw0 = As + wave * 512;  bhalf_t* Asw1 = As + (wave + 4) * 512;
  bhalf_t* Bsw0 = Bs + wave * 512;  bhalf_t* Bsw1 = Bs + (wave + 4) * 512;

  for (int k0 = 0; k0 < 1024; k0 += 32) {
    GLD16(Ab0 + k0, Asw0);
    GLD16(Ab1 + k0, Asw1);
    GLD16(Bb0 + k0, Bsw0);
    GLD16(Bb1 + k0, Bsw1);
    __syncthreads();
    bf16x8 af[4], bfr[4];
#pragma unroll
    for (int i = 0; i < 4; ++i)
      af[i] = *(const bf16x8*)(As + (wm * 64 + i * 16 + tn) * 32 + quad * 8);
#pragma unroll
    for (int j = 0; j < 4; ++j)
      bfr[j] = *(const bf16x8*)(Bs + (wn * 64 + j * 16 + tn) * 32 + quad * 8);
#pragma unroll
    for (int i = 0; i < 4; ++i)
#pragma unroll
      for (int j = 0; j < 4; ++j)
        acc[i][j] = __builtin_amdgcn_mfma_f32_16x16x32_bf16(af[i], bfr[j], acc[i][j], 0, 0, 0);
    __syncthreads();
  }
}

// ---------------------------------------------------------------------------
// Fused q/k/v projection.  q scaled by 0.125*log2e (attn uses exp2).
// v stored transposed [bh][dk][s] with s sigma-permuted (swap bits 2<->3).
// ---------------------------------------------------------------------------
__global__ __launch_bounds__(256) void proj_gemm(
    const bhalf_t* __restrict__ Qb, const bhalf_t* __restrict__ Kb, const bhalf_t* __restrict__ Vb,
    const bhalf_t* __restrict__ Wqb, const bhalf_t* __restrict__ Wkb, const bhalf_t* __restrict__ Wvb,
    const float* __restrict__ bq, const float* __restrict__ bk, const float* __restrict__ bv,
    bhalf_t* __restrict__ qo, bhalf_t* __restrict__ ko, bhalf_t* __restrict__ vto)
{
  __shared__ bhalf_t As[4096];
  __shared__ bhalf_t Bs[4096];
  const int seg = blockIdx.x >> 9;
  const int idx = blockIdx.x & 511;
  const int bm = idx >> 3, bn = idx & 7;

  const bhalf_t *A, *Bw; const float* bias; bhalf_t* out; float scale; int mode;
  if (seg == 0)      { A = Qb; Bw = Wqb; bias = bq; out = qo;  scale = 0.18033688f; mode = 0; }
  else if (seg == 1) { A = Kb; Bw = Wkb; bias = bk; out = ko;  scale = 1.0f;        mode = 0; }
  else               { A = Vb; Bw = Wvb; bias = bv; out = vto; scale = 1.0f;        mode = 1; }

  f32x4 acc[4][4];
#pragma unroll
  for (int i = 0; i < 4; ++i)
#pragma unroll
    for (int j = 0; j < 4; ++j)
      acc[i][j] = (f32x4){0.f, 0.f, 0.f, 0.f};

  gemm_core_128(A, Bw, bm, bn, As, Bs, acc);

  const int lane = threadIdx.x & 63, wave = threadIdx.x >> 6;
  const int wm = wave >> 1, wn = wave & 1, quad = lane >> 4, tn = lane & 15;
#pragma unroll
  for (int i = 0; i < 4; ++i)
#pragma unroll
    for (int j = 0; j < 4; ++j) {
      const int n = bn * 128 + wn * 64 + j * 16 + tn;
      const float bsv = bias[n];
      const int h = n >> 6, dk = n & 63;
#pragma unroll
      for (int r = 0; r < 4; ++r) {
        const int m = bm * 128 + wm * 64 + i * 16 + quad * 4 + r;
        const int b = m >> 11, s = m & 2047;
        const float v = (acc[i][j][r] + bsv) * scale;
        size_t addr;
        if (mode == 0) addr = (((size_t)(b * 16 + h)) * 2048 + s) * 64 + dk;
        else {
          const int s2 = (s & ~12) | ((s & 4) << 1) | ((s & 8) >> 1);  // sigma
          addr = (((size_t)(b * 16 + h)) * 64 + dk) * 2048 + s2;
        }
        out[addr] = (bhalf_t)v;
      }
    }
}

// ---------------------------------------------------------------------------
__global__ __launch_bounds__(256) void out_gemm(
    const bhalf_t* __restrict__ A, const bhalf_t* __restrict__ Bw,
    const float* __restrict__ bias, float* __restrict__ Cout)
{
  __shared__ bhalf_t As[4096];
  __shared__ bhalf_t Bs[4096];
  const int bm = blockIdx.x >> 3, bn = blockIdx.x & 7;

  f32x4 acc[4][4];
#pragma unroll
  for (int i = 0; i < 4; ++i)
#pragma unroll
    for (int j = 0; j < 4; ++j)
      acc[i][j] = (f32x4){0.f, 0.f, 0.f, 0.f};

  gemm_core_128(A, Bw, bm, bn, As, Bs, acc);

  const int lane = threadIdx.x & 63, wave = threadIdx.x >> 6;
  const int wm = wave >> 1, wn = wave & 1, quad = lane >> 4, tn = lane & 15;
#pragma unroll
  for (int i = 0; i < 4; ++i)
#pragma unroll
    for (int j = 0; j < 4; ++j) {
      const int n = bn * 128 + wn * 64 + j * 16 + tn;
      const float bsv = bias[n];
#pragma unroll
      for (int r = 0; r < 4; ++r) {
        const int m = bm * 128 + wm * 64 + i * 16 + quad * 4 + r;
        Cout[(size_t)m * 1024 + n] = acc[i][j][r] + bsv;
      }
    }
}

// ---------------------------------------------------------------------------
// Flash attention v3.  Block = 4 waves x 64 q rows = 256 q; kv tiles of 64.
// S^T = K @ Q^T (A=K LDS, B=Q regs).  P stays in registers: V^T is stored
// sigma-permuted so the S^T C-layout regs [8kb..8kb+7], exp'd+packed, ARE the
// PV B-fragment for k-block kb.  O^T = Vt @ P accumulates in regs.
// ---------------------------------------------------------------------------
__global__ __launch_bounds__(256, 2) void attn_kernel(
    const bhalf_t* __restrict__ qp, const bhalf_t* __restrict__ kp,
    const bhalf_t* __restrict__ vtp, bhalf_t* __restrict__ outp)
{
  __shared__ bhalf_t Klds[4096];    // [64 kv][64 dk], 16B chunks XOR-swizzled
  __shared__ bhalf_t Vtlds[4096];   // [64 dk][64 kv(sigma)], XOR-swizzled

  const int tid = threadIdx.x, lane = tid & 63, wave = tid >> 6;
  const int q31 = lane & 31, h = lane >> 5;
  const int bh = blockIdx.y, qt = blockIdx.x;

  // Q B-fragments: qf[qset][ks][j] = Q[srow][ks*16 + h*8 + j]
  const bhalf_t* qbase = qp + (((size_t)bh * 2048) + qt * 256 + wave * 64 + q31) * 64;
  bf16x8 qf[2][4];
#pragma unroll
  for (int qs = 0; qs < 2; ++qs)
#pragma unroll
    for (int ks = 0; ks < 4; ++ks)
      qf[qs][ks] = *(const bf16x8*)(qbase + qs * 32 * 64 + ks * 16 + h * 8);

  f32x16 Ot[2][2];
#pragma unroll
  for (int qs = 0; qs < 2; ++qs)
#pragma unroll
    for (int dd = 0; dd < 2; ++dd)
#pragma unroll
      for (int i = 0; i < 16; ++i) Ot[qs][dd][i] = 0.f;
  float Lp[2] = {0.f, 0.f};

  const bhalf_t* kbase  = kp  + (size_t)bh * 2048 * 64;
  const bhalf_t* vtbase = vtp + (size_t)bh * 64 * 2048;

  const int rloc = lane >> 3;                 // staging row within 8-row chunk
  const int cg8  = ((lane & 7) ^ rloc) * 8;   // swizzled source chunk (elems)
  const int q7 = q31 & 7;

  for (int kv0 = 0; kv0 < 2048; kv0 += 64) {
    // stage K [64][64] and Vt [64][64]: 16 x 1KB GLD16 per block
#pragma unroll
    for (int i = 0; i < 2; ++i) {
      const int r0 = (wave * 2 + i) * 8;
      GLD16(kbase + (size_t)(kv0 + r0 + rloc) * 64 + cg8, Klds + r0 * 64);
      GLD16(vtbase + (size_t)(r0 + rloc) * 2048 + kv0 + cg8, Vtlds + r0 * 64);
    }
    __syncthreads();

    // S^T + exp2 + pack into PV B-fragments (register-only)
    bf16x8 pb[2][4];
#pragma unroll
    for (int mb = 0; mb < 2; ++mb) {
      bf16x8 ka[4];
#pragma unroll
      for (int ks = 0; ks < 4; ++ks)
        ka[ks] = *(const bf16x8*)(Klds + (mb * 32 + q31) * 64 + ((2 * ks + h) ^ q7) * 8);
#pragma unroll
      for (int qs = 0; qs < 2; ++qs) {
        f32x16 S;
#pragma unroll
        for (int i = 0; i < 16; ++i) S[i] = 0.f;
#pragma unroll
        for (int ks = 0; ks < 4; ++ks)
          S = __builtin_amdgcn_mfma_f32_32x32x16_bf16(ka[ks], qf[qs][ks], S, 0, 0, 0);
        float ls = 0.f;
#pragma unroll
        for (int half = 0; half < 2; ++half) {
          bf16x8 pk;
#pragma unroll
          for (int j = 0; j < 8; ++j) {
            const float e = __builtin_amdgcn_exp2f(S[half * 8 + j]);
            ls += e;
            pk[j] = (bhalf_t)e;
          }
          pb[qs][mb * 2 + half] = pk;
        }
        Lp[qs] += ls;
      }
    }

    // O^T += Vt @ P   (A-frag k-order matches sigma-permuted storage)
#pragma unroll
    for (int dd = 0; dd < 2; ++dd)
#pragma unroll
      for (int kb = 0; kb < 4; ++kb) {
        const bf16x8 va = *(const bf16x8*)(Vtlds + (dd * 32 + q31) * 64 + ((2 * kb + h) ^ q7) * 8);
#pragma unroll
        for (int qs = 0; qs < 2; ++qs)
          Ot[qs][dd] = __builtin_amdgcn_mfma_f32_32x32x16_bf16(va, pb[qs][kb], Ot[qs][dd], 0, 0, 0);
      }
    __syncthreads();
  }

  // normalize (per-lane q) and store packed bf16x4
  const int b = bh >> 4, hh = bh & 15;
#pragma unroll
  for (int qs = 0; qs < 2; ++qs) {
    const float Lt = Lp[qs] + __shfl_xor(Lp[qs], 32, 64);
    const float linv = 1.0f / Lt;
    const int s = qt * 256 + wave * 64 + qs * 32 + q31;
    bhalf_t* ob = outp + ((size_t)(b * 2048 + s)) * 1024 + hh * 64;
#pragma unroll
    for (int dd = 0; dd < 2; ++dd)
#pragma unroll
      for (int g = 0; g < 4; ++g) {
        bf16x4 o;
        o.x = (bhalf_t)(Ot[qs][dd][4 * g + 0] * linv);
        o.y = (bhalf_t)(Ot[qs][dd][4 * g + 1] * linv);
        o.z = (bhalf_t)(Ot[qs][dd][4 * g + 2] * linv);
        o.w = (bhalf_t)(Ot[qs][dd][4 * g + 3] * linv);
        *(bf16x4*)(ob + dd * 32 + g * 8 + h * 4) = o;
      }
  }
}

// ---------------------------------------------------------------------------
extern "C" void kernel_launch(void* const* d_in, const int* in_sizes, int n_in,
                              void* d_out, int out_size, void* d_ws, size_t ws_size,
                              hipStream_t stream)
{
  const float* Q  = (const float*)d_in[0];
  const float* K  = (const float*)d_in[1];
  const float* V  = (const float*)d_in[2];
  const float* Wq = (const float*)d_in[3];
  const float* bq = (const float*)d_in[4];
  const float* Wk = (const float*)d_in[5];
  const float* bk = (const float*)d_in[6];
  const float* Wv = (const float*)d_in[7];
  const float* bv = (const float*)d_in[8];
  const float* Wo = (const float*)d_in[9];
  const float* bo = (const float*)d_in[10];

  char* ws = (char*)d_ws;
  const size_t SZ = 8192ull * 1024 * 2;   // 16 MB  [8192,1024] bf16
  const size_t WZ = 1024ull * 1024 * 2;   //  2 MB  [1024,1024] bf16
  bhalf_t* Qb   = (bhalf_t*)(ws);
  bhalf_t* Kb   = (bhalf_t*)(ws + SZ);
  bhalf_t* Vb   = (bhalf_t*)(ws + 2 * SZ);
  bhalf_t* Wqb  = (bhalf_t*)(ws + 3 * SZ);
  bhalf_t* Wkb  = (bhalf_t*)(ws + 3 * SZ + WZ);
  bhalf_t* Wvb  = (bhalf_t*)(ws + 3 * SZ + 2 * WZ);
  bhalf_t* Wob  = (bhalf_t*)(ws + 3 * SZ + 3 * WZ);
  bhalf_t* q_p  = (bhalf_t*)(ws + 3 * SZ + 4 * WZ);
  bhalf_t* k_p  = (bhalf_t*)(ws + 4 * SZ + 4 * WZ);
  bhalf_t* vt_p = (bhalf_t*)(ws + 5 * SZ + 4 * WZ);
  bhalf_t* attn_o = Qb;   // alias: Qb is dead after proj_gemm

  cvt_all<<<28672, 256, 0, stream>>>(Q, K, V, Wq, Wk, Wv, Wo,
                                     Qb, Kb, Vb, Wqb, Wkb, Wvb, Wob);
  proj_gemm<<<1536, 256, 0, stream>>>(Qb, Kb, Vb, Wqb, Wkb, Wvb,
                                      bq, bk, bv, q_p, k_p, vt_p);
  attn_kernel<<<dim3(8, 64), 256, 0, stream>>>(q_p, k_p, vt_p, attn_o);
  out_gemm<<<512, 256, 0, stream>>>(attn_o, Wob, bo, (float*)d_out);
}

// Round 4
// 334.663 us; speedup vs baseline: 1.2363x; 1.0424x over previous
//
#include <hip/hip_runtime.h>

// B=4, S=2048, D=1024, H=16, Dk=64.  M = B*S = 8192.
// cvt(fp32->bf16) -> proj GEMMs (q/k [bh][s][dk], v^T sigma-permuted [bh][dk][s],
// q pre-scaled 0.125*log2e) -> flash attn v3 (S^T 32x32x16, P-in-regs via sigma
// trick, 64 q/wave) -> out GEMM.  GEMM block mapping is XCD-aware: bm fast
// (XCD = bm%8) so each XCD's L2 holds a 2MB A-slab set reused across bn.
// Workspace: 104 MB.

typedef __bf16 bhalf_t;
typedef __attribute__((ext_vector_type(8)))  __bf16 bf16x8;
typedef __attribute__((ext_vector_type(4)))  __bf16 bf16x4;
typedef __attribute__((ext_vector_type(4)))  float  f32x4;
typedef __attribute__((ext_vector_type(16))) float  f32x16;

typedef __attribute__((address_space(1))) void gvoid_t;
typedef __attribute__((address_space(3))) void lvoid_t;
#define GLD16(g, l) __builtin_amdgcn_global_load_lds((const gvoid_t*)(g), (lvoid_t*)(l), 16, 0, 0)

// ---------------------------------------------------------------------------
__global__ __launch_bounds__(256) void cvt_all(
    const float* __restrict__ Q, const float* __restrict__ Kin, const float* __restrict__ V,
    const float* __restrict__ Wq, const float* __restrict__ Wk, const float* __restrict__ Wv,
    const float* __restrict__ Wo,
    bhalf_t* __restrict__ Qb, bhalf_t* __restrict__ Kb, bhalf_t* __restrict__ Vb,
    bhalf_t* __restrict__ Wqb, bhalf_t* __restrict__ Wkb, bhalf_t* __restrict__ Wvb,
    bhalf_t* __restrict__ Wob)
{
  size_t t = (size_t)blockIdx.x * 256 + threadIdx.x;   // float4 index
  const float* src; bhalf_t* dst;
  if (t < 2097152)      { src = Q;   dst = Qb; }
  else if (t < 4194304) { src = Kin; dst = Kb; t -= 2097152; }
  else if (t < 6291456) { src = V;   dst = Vb; t -= 4194304; }
  else {
    t -= 6291456;
    int w = (int)(t >> 18); t &= 262143;
    src = (w == 0) ? Wq  : (w == 1) ? Wk  : (w == 2) ? Wv  : Wo;
    dst = (w == 0) ? Wqb : (w == 1) ? Wkb : (w == 2) ? Wvb : Wob;
  }
  float4 f = ((const float4*)src)[t];
  bf16x4 o;
  o.x = (bhalf_t)f.x; o.y = (bhalf_t)f.y; o.z = (bhalf_t)f.z; o.w = (bhalf_t)f.w;
  ((bf16x4*)dst)[t] = o;
}

// ---------------------------------------------------------------------------
// m97-style GEMM core: C[128x128] tile of A[M,1024] @ B[1024,1024(rows=N)]^T
// ---------------------------------------------------------------------------
__device__ __forceinline__ void gemm_core_128(
    const bhalf_t* __restrict__ A, const bhalf_t* __restrict__ B,
    int bm, int bn, bhalf_t* As, bhalf_t* Bs, f32x4 acc[4][4])
{
  const int tid = threadIdx.x, lane = tid & 63, wave = tid >> 6;
  const int wm = wave >> 1, wn = wave & 1;
  const int quad = lane >> 4, tn = lane & 15;
  const int srow = lane >> 2, scol = (lane & 3) * 8;

  const bhalf_t* Ab0 = A + (size_t)(bm * 128 + wave * 16 + srow) * 1024 + scol;
  const bhalf_t* Ab1 = Ab0 + (size_t)64 * 1024;
  const bhalf_t* Bb0 = B + (size_t)(bn * 128 + wave * 16 + srow) * 1024 + scol;
  const bhalf_t* Bb1 = Bb0 + (size_t)64 * 1024;
  bhalf_t* Asw0 = As + wave * 512;  bhalf_t* Asw1 = As + (wave + 4) * 512;
  bhalf_t* Bsw0 = Bs + wave * 512;  bhalf_t* Bsw1 = Bs + (wave + 4) * 512;

  for (int k0 = 0; k0 < 1024; k0 += 32) {
    GLD16(Ab0 + k0, Asw0);
    GLD16(Ab1 + k0, Asw1);
    GLD16(Bb0 + k0, Bsw0);
    GLD16(Bb1 + k0, Bsw1);
    __syncthreads();
    bf16x8 af[4], bfr[4];
#pragma unroll
    for (int i = 0; i < 4; ++i)
      af[i] = *(const bf16x8*)(As + (wm * 64 + i * 16 + tn) * 32 + quad * 8);
#pragma unroll
    for (int j = 0; j < 4; ++j)
      bfr[j] = *(const bf16x8*)(Bs + (wn * 64 + j * 16 + tn) * 32 + quad * 8);
#pragma unroll
    for (int i = 0; i < 4; ++i)
#pragma unroll
      for (int j = 0; j < 4; ++j)
        acc[i][j] = __builtin_amdgcn_mfma_f32_16x16x32_bf16(af[i], bfr[j], acc[i][j], 0, 0, 0);
    __syncthreads();
  }
}

// ---------------------------------------------------------------------------
// Fused q/k/v projection.  q scaled by 0.125*log2e (attn uses exp2).
// v stored transposed [bh][dk][s] with s sigma-permuted (swap bits 2<->3).
// Block mapping: bm = idx&63 (fast) so XCD = bm%8 -> per-XCD A-slab reuse.
// ---------------------------------------------------------------------------
__global__ __launch_bounds__(256) void proj_gemm(
    const bhalf_t* __restrict__ Qb, const bhalf_t* __restrict__ Kb, const bhalf_t* __restrict__ Vb,
    const bhalf_t* __restrict__ Wqb, const bhalf_t* __restrict__ Wkb, const bhalf_t* __restrict__ Wvb,
    const float* __restrict__ bq, const float* __restrict__ bk, const float* __restrict__ bv,
    bhalf_t* __restrict__ qo, bhalf_t* __restrict__ ko, bhalf_t* __restrict__ vto)
{
  __shared__ bhalf_t As[4096];
  __shared__ bhalf_t Bs[4096];
  const int seg = blockIdx.x >> 9;
  const int idx = blockIdx.x & 511;
  const int bm = idx & 63, bn = idx >> 6;    // XCD-aware: bm fast-varying

  const bhalf_t *A, *Bw; const float* bias; bhalf_t* out; float scale; int mode;
  if (seg == 0)      { A = Qb; Bw = Wqb; bias = bq; out = qo;  scale = 0.18033688f; mode = 0; }
  else if (seg == 1) { A = Kb; Bw = Wkb; bias = bk; out = ko;  scale = 1.0f;        mode = 0; }
  else               { A = Vb; Bw = Wvb; bias = bv; out = vto; scale = 1.0f;        mode = 1; }

  f32x4 acc[4][4];
#pragma unroll
  for (int i = 0; i < 4; ++i)
#pragma unroll
    for (int j = 0; j < 4; ++j)
      acc[i][j] = (f32x4){0.f, 0.f, 0.f, 0.f};

  gemm_core_128(A, Bw, bm, bn, As, Bs, acc);

  const int lane = threadIdx.x & 63, wave = threadIdx.x >> 6;
  const int wm = wave >> 1, wn = wave & 1, quad = lane >> 4, tn = lane & 15;
#pragma unroll
  for (int i = 0; i < 4; ++i)
#pragma unroll
    for (int j = 0; j < 4; ++j) {
      const int n = bn * 128 + wn * 64 + j * 16 + tn;
      const float bsv = bias[n];
      const int h = n >> 6, dk = n & 63;
#pragma unroll
      for (int r = 0; r < 4; ++r) {
        const int m = bm * 128 + wm * 64 + i * 16 + quad * 4 + r;
        const int b = m >> 11, s = m & 2047;
        const float v = (acc[i][j][r] + bsv) * scale;
        size_t addr;
        if (mode == 0) addr = (((size_t)(b * 16 + h)) * 2048 + s) * 64 + dk;
        else {
          const int s2 = (s & ~12) | ((s & 4) << 1) | ((s & 8) >> 1);  // sigma
          addr = (((size_t)(b * 16 + h)) * 64 + dk) * 2048 + s2;
        }
        out[addr] = (bhalf_t)v;
      }
    }
}

// ---------------------------------------------------------------------------
__global__ __launch_bounds__(256) void out_gemm(
    const bhalf_t* __restrict__ A, const bhalf_t* __restrict__ Bw,
    const float* __restrict__ bias, float* __restrict__ Cout)
{
  __shared__ bhalf_t As[4096];
  __shared__ bhalf_t Bs[4096];
  const int bm = blockIdx.x & 63, bn = blockIdx.x >> 6;   // XCD-aware

  f32x4 acc[4][4];
#pragma unroll
  for (int i = 0; i < 4; ++i)
#pragma unroll
    for (int j = 0; j < 4; ++j)
      acc[i][j] = (f32x4){0.f, 0.f, 0.f, 0.f};

  gemm_core_128(A, Bw, bm, bn, As, Bs, acc);

  const int lane = threadIdx.x & 63, wave = threadIdx.x >> 6;
  const int wm = wave >> 1, wn = wave & 1, quad = lane >> 4, tn = lane & 15;
#pragma unroll
  for (int i = 0; i < 4; ++i)
#pragma unroll
    for (int j = 0; j < 4; ++j) {
      const int n = bn * 128 + wn * 64 + j * 16 + tn;
      const float bsv = bias[n];
#pragma unroll
      for (int r = 0; r < 4; ++r) {
        const int m = bm * 128 + wm * 64 + i * 16 + quad * 4 + r;
        Cout[(size_t)m * 1024 + n] = acc[i][j][r] + bsv;
      }
    }
}

// ---------------------------------------------------------------------------
// Flash attention v3.  Block = 4 waves x 64 q rows = 256 q; kv tiles of 64.
// S^T = K @ Q^T (A=K LDS, B=Q regs).  P stays in registers: V^T is stored
// sigma-permuted so the S^T C-layout regs [8kb..8kb+7], exp'd+packed, ARE the
// PV B-fragment for k-block kb.  O^T = Vt @ P accumulates in regs.
// ---------------------------------------------------------------------------
__global__ __launch_bounds__(256, 2) void attn_kernel(
    const bhalf_t* __restrict__ qp, const bhalf_t* __restrict__ kp,
    const bhalf_t* __restrict__ vtp, bhalf_t* __restrict__ outp)
{
  __shared__ bhalf_t Klds[4096];    // [64 kv][64 dk], 16B chunks XOR-swizzled
  __shared__ bhalf_t Vtlds[4096];   // [64 dk][64 kv(sigma)], XOR-swizzled

  const int tid = threadIdx.x, lane = tid & 63, wave = tid >> 6;
  const int q31 = lane & 31, h = lane >> 5;
  const int bh = blockIdx.y, qt = blockIdx.x;

  // Q B-fragments: qf[qset][ks][j] = Q[srow][ks*16 + h*8 + j]
  const bhalf_t* qbase = qp + (((size_t)bh * 2048) + qt * 256 + wave * 64 + q31) * 64;
  bf16x8 qf[2][4];
#pragma unroll
  for (int qs = 0; qs < 2; ++qs)
#pragma unroll
    for (int ks = 0; ks < 4; ++ks)
      qf[qs][ks] = *(const bf16x8*)(qbase + qs * 32 * 64 + ks * 16 + h * 8);

  f32x16 Ot[2][2];
#pragma unroll
  for (int qs = 0; qs < 2; ++qs)
#pragma unroll
    for (int dd = 0; dd < 2; ++dd)
#pragma unroll
      for (int i = 0; i < 16; ++i) Ot[qs][dd][i] = 0.f;
  float Lp[2] = {0.f, 0.f};

  const bhalf_t* kbase  = kp  + (size_t)bh * 2048 * 64;
  const bhalf_t* vtbase = vtp + (size_t)bh * 64 * 2048;

  const int rloc = lane >> 3;                 // staging row within 8-row chunk
  const int cg8  = ((lane & 7) ^ rloc) * 8;   // swizzled source chunk (elems)
  const int q7 = q31 & 7;

  for (int kv0 = 0; kv0 < 2048; kv0 += 64) {
    // stage K [64][64] and Vt [64][64]: 16 x 1KB GLD16 per block
#pragma unroll
    for (int i = 0; i < 2; ++i) {
      const int r0 = (wave * 2 + i) * 8;
      GLD16(kbase + (size_t)(kv0 + r0 + rloc) * 64 + cg8, Klds + r0 * 64);
      GLD16(vtbase + (size_t)(r0 + rloc) * 2048 + kv0 + cg8, Vtlds + r0 * 64);
    }
    __syncthreads();

    // S^T + exp2 + pack into PV B-fragments (register-only)
    bf16x8 pb[2][4];
#pragma unroll
    for (int mb = 0; mb < 2; ++mb) {
      bf16x8 ka[4];
#pragma unroll
      for (int ks = 0; ks < 4; ++ks)
        ka[ks] = *(const bf16x8*)(Klds + (mb * 32 + q31) * 64 + ((2 * ks + h) ^ q7) * 8);
#pragma unroll
      for (int qs = 0; qs < 2; ++qs) {
        f32x16 S;
#pragma unroll
        for (int i = 0; i < 16; ++i) S[i] = 0.f;
#pragma unroll
        for (int ks = 0; ks < 4; ++ks)
          S = __builtin_amdgcn_mfma_f32_32x32x16_bf16(ka[ks], qf[qs][ks], S, 0, 0, 0);
        float ls = 0.f;
#pragma unroll
        for (int half = 0; half < 2; ++half) {
          bf16x8 pk;
#pragma unroll
          for (int j = 0; j < 8; ++j) {
            const float e = __builtin_amdgcn_exp2f(S[half * 8 + j]);
            ls += e;
            pk[j] = (bhalf_t)e;
          }
          pb[qs][mb * 2 + half] = pk;
        }
        Lp[qs] += ls;
      }
    }

    // O^T += Vt @ P   (A-frag k-order matches sigma-permuted storage)
#pragma unroll
    for (int dd = 0; dd < 2; ++dd)
#pragma unroll
      for (int kb = 0; kb < 4; ++kb) {
        const bf16x8 va = *(const bf16x8*)(Vtlds + (dd * 32 + q31) * 64 + ((2 * kb + h) ^ q7) * 8);
#pragma unroll
        for (int qs = 0; qs < 2; ++qs)
          Ot[qs][dd] = __builtin_amdgcn_mfma_f32_32x32x16_bf16(va, pb[qs][kb], Ot[qs][dd], 0, 0, 0);
      }
    __syncthreads();
  }

  // normalize (per-lane q) and store packed bf16x4
  const int b = bh >> 4, hh = bh & 15;
#pragma unroll
  for (int qs = 0; qs < 2; ++qs) {
    const float Lt = Lp[qs] + __shfl_xor(Lp[qs], 32, 64);
    const float linv = 1.0f / Lt;
    const int s = qt * 256 + wave * 64 + qs * 32 + q31;
    bhalf_t* ob = outp + ((size_t)(b * 2048 + s)) * 1024 + hh * 64;
#pragma unroll
    for (int dd = 0; dd < 2; ++dd)
#pragma unroll
      for (int g = 0; g < 4; ++g) {
        bf16x4 o;
        o.x = (bhalf_t)(Ot[qs][dd][4 * g + 0] * linv);
        o.y = (bhalf_t)(Ot[qs][dd][4 * g + 1] * linv);
        o.z = (bhalf_t)(Ot[qs][dd][4 * g + 2] * linv);
        o.w = (bhalf_t)(Ot[qs][dd][4 * g + 3] * linv);
        *(bf16x4*)(ob + dd * 32 + g * 8 + h * 4) = o;
      }
  }
}

// ---------------------------------------------------------------------------
extern "C" void kernel_launch(void* const* d_in, const int* in_sizes, int n_in,
                              void* d_out, int out_size, void* d_ws, size_t ws_size,
                              hipStream_t stream)
{
  const float* Q  = (const float*)d_in[0];
  const float* K  = (const float*)d_in[1];
  const float* V  = (const float*)d_in[2];
  const float* Wq = (const float*)d_in[3];
  const float* bq = (const float*)d_in[4];
  const float* Wk = (const float*)d_in[5];
  const float* bk = (const float*)d_in[6];
  const float* Wv = (const float*)d_in[7];
  const float* bv = (const float*)d_in[8];
  const float* Wo = (const float*)d_in[9];
  const float* bo = (const float*)d_in[10];

  char* ws = (char*)d_ws;
  const size_t SZ = 8192ull * 1024 * 2;   // 16 MB  [8192,1024] bf16
  const size_t WZ = 1024ull * 1024 * 2;   //  2 MB  [1024,1024] bf16
  bhalf_t* Qb   = (bhalf_t*)(ws);
  bhalf_t* Kb   = (bhalf_t*)(ws + SZ);
  bhalf_t* Vb   = (bhalf_t*)(ws + 2 * SZ);
  bhalf_t* Wqb  = (bhalf_t*)(ws + 3 * SZ);
  bhalf_t* Wkb  = (bhalf_t*)(ws + 3 * SZ + WZ);
  bhalf_t* Wvb  = (bhalf_t*)(ws + 3 * SZ + 2 * WZ);
  bhalf_t* Wob  = (bhalf_t*)(ws + 3 * SZ + 3 * WZ);
  bhalf_t* q_p  = (bhalf_t*)(ws + 3 * SZ + 4 * WZ);
  bhalf_t* k_p  = (bhalf_t*)(ws + 4 * SZ + 4 * WZ);
  bhalf_t* vt_p = (bhalf_t*)(ws + 5 * SZ + 4 * WZ);
  bhalf_t* attn_o = Qb;   // alias: Qb is dead after proj_gemm

  cvt_all<<<28672, 256, 0, stream>>>(Q, K, V, Wq, Wk, Wv, Wo,
                                     Qb, Kb, Vb, Wqb, Wkb, Wvb, Wob);
  proj_gemm<<<1536, 256, 0, stream>>>(Qb, Kb, Vb, Wqb, Wkb, Wvb,
                                      bq, bk, bv, q_p, k_p, vt_p);
  attn_kernel<<<dim3(8, 64), 256, 0, stream>>>(q_p, k_p, vt_p, attn_o);
  out_gemm<<<512, 256, 0, stream>>>(attn_o, Wob, bo, (float*)d_out);
}